// Round 8
// baseline (41.044 us; speedup 1.0000x reference)
//
#include <hip/hip_runtime.h>
#include <hip/hip_bf16.h>
#include <math.h>

// v7: barrier-free fused MLP (v4 structure) + deep prefetch.
//  - prep_pack: weights fp32->bf16 in MFMA-fragment order (1KB/frag) in d_ws.
//  - main: ZERO barriers. Each wave owns 16 batch rows, full N per layer.
//    Layer transposes via wave-private 8KB LDS (same-wave DS ordering).
//  - NEW vs v4: x prefetch depth 4 (rotating float4 slots), B-frag ping-pong
//    depth 2, L2/L3 fragment groups preloaded before LDS transposes.
//  - launch_bounds(256,2): VGPR budget ~256, grid 512 blocks -> 8 waves/CU.

#define TPB 256

// packed-weight offsets (shorts): w1p [25kt][8nf][64][8], w2p [4kt][16nf][64][8], w3p [8kt][64][8]
#define W2P 102400     // 200*512
#define W3P 135168     // 264*512
#define NFRAG_TOT 272
#define WTOT (NFRAG_TOT * 512)

typedef __attribute__((ext_vector_type(8))) short bf16x8;
typedef __attribute__((ext_vector_type(4))) float f32x4;

static __device__ inline short f2bf(float f) {
    union { float f; unsigned u; } v; v.f = f;
    unsigned r = v.u + 0x7fffu + ((v.u >> 16) & 1u);   // RNE
    return (short)(r >> 16);
}
static __device__ inline bf16x8 cvt8(float4 a, float4 b) {
    union { __hip_bfloat162 h2[4]; bf16x8 v; } u;
    u.h2[0] = __float22bfloat162_rn(make_float2(a.x, a.y));
    u.h2[1] = __float22bfloat162_rn(make_float2(a.z, a.w));
    u.h2[2] = __float22bfloat162_rn(make_float2(b.x, b.y));
    u.h2[3] = __float22bfloat162_rn(make_float2(b.z, b.w));
    return u.v;
}
static __device__ inline float4 ld4g(const float* p, bool ok) {
    return ok ? *reinterpret_cast<const float4*>(p) : make_float4(0.f,0.f,0.f,0.f);
}

__global__ void prep_pack(const float* __restrict__ w1,
                          const float* __restrict__ w2,
                          const float* __restrict__ w3,
                          short* __restrict__ wb) {
    const int tid = blockIdx.x * blockDim.x + threadIdx.x;   // one per (frag, lane)
    if (tid >= NFRAG_TOT * 64) return;
    const int fg = tid >> 6, lane = tid & 63;
    const int l15 = lane & 15, l4 = lane >> 4;
    float4 va = make_float4(0,0,0,0), vb = va;
    if (fg < 200) {                       // w1: kt = fg>>3 (0..24), nf = fg&7
        const int kt = fg >> 3, nf = fg & 7;
        const int kg = kt * 32 + l4 * 8;
        if (kg + 8 <= 784) {
            const float* p = &w1[(size_t)(nf * 16 + l15) * 784 + kg];
            va = *(const float4*)p; vb = *(const float4*)(p + 4);
        }
    } else if (fg < 264) {                // w2: 4 kt x 16 nf
        const int g = fg - 200, kt = g >> 4, nf = g & 15;
        const float* p = &w2[(size_t)(nf * 16 + l15) * 128 + kt * 32 + l4 * 8];
        va = *(const float4*)p; vb = *(const float4*)(p + 4);
    } else {                              // w3: 8 kt, classes on l15 (>=10 zero)
        const int kt = fg - 264;
        if (l15 < 10) {
            const float* p = &w3[(size_t)l15 * 256 + kt * 32 + l4 * 8];
            va = *(const float4*)p; vb = *(const float4*)(p + 4);
        }
    }
    *(bf16x8*)&wb[(size_t)tid * 8] = cvt8(va, vb);
}

__global__ __launch_bounds__(TPB, 2) void mnist_v7(
    const float* __restrict__ x,    // [32768,784]
    const float* __restrict__ b1v,  // [128]
    const float* __restrict__ b2v,  // [256]
    const float* __restrict__ b3v,  // [10]
    const short* __restrict__ wb,   // packed bf16 weights
    float* __restrict__ out)        // [32768,10]
{
    __shared__ __align__(16) short s_h[4][4096];   // 8KB/wave: h1 [16][128], then h2 [16][256] overlay

    const int t    = threadIdx.x;
    const int lane = t & 63;
    const int wv   = t >> 6;
    const int l15  = lane & 15;
    const int l4   = lane >> 4;
    const int r0   = blockIdx.x * 64 + wv * 16;
    short* const hb = &s_h[wv][0];

    const float* xrow = &x[(size_t)(r0 + l15) * 784];

    // ================= Layer 1: 25 K-tiles of 32, depth-4 x / depth-2 B =======
    f32x4 acc1[8];
    #pragma unroll
    for (int nf = 0; nf < 8; ++nf) acc1[nf] = (f32x4){0.f,0.f,0.f,0.f};

    float4 xa[4], xb[4];
    #pragma unroll
    for (int p = 0; p < 4; ++p) {
        const int kg = p * 32 + l4 * 8;
        xa[p] = ld4g(xrow + kg, true);
        xb[p] = ld4g(xrow + kg + 4, true);
    }
    bf16x8 bA[8], bB[8];
    #pragma unroll
    for (int nf = 0; nf < 8; ++nf) bA[nf] = *(const bf16x8*)&wb[(size_t)(0 * 8 + nf) * 512 + lane * 8];
    #pragma unroll
    for (int nf = 0; nf < 8; ++nf) bB[nf] = *(const bf16x8*)&wb[(size_t)(1 * 8 + nf) * 512 + lane * 8];

    for (int kt = 0; kt < 24; kt += 2) {
        {   // even sub-iter: consume xa[kt&3], bA
            const int cur = kt & 3;
            const bf16x8 a = cvt8(xa[cur], xb[cur]);
            if (kt + 4 <= 24) {                       // refill x slot with tile kt+4
                const int kg = (kt + 4) * 32 + l4 * 8;
                const bool ok = kg + 8 <= 784;
                xa[cur] = ld4g(xrow + kg, ok);
                xb[cur] = ld4g(xrow + kg + 4, ok);
            }
            #pragma unroll
            for (int nf = 0; nf < 8; ++nf)
                acc1[nf] = __builtin_amdgcn_mfma_f32_16x16x32_bf16(a, bA[nf], acc1[nf], 0, 0, 0);
            #pragma unroll
            for (int nf = 0; nf < 8; ++nf)            // kt+2 <= 24 always here
                bA[nf] = *(const bf16x8*)&wb[(size_t)((kt + 2) * 8 + nf) * 512 + lane * 8];
        }
        {   // odd sub-iter kt+1: consume xa[(kt+1)&3], bB
            const int cur = (kt + 1) & 3;
            const bf16x8 a = cvt8(xa[cur], xb[cur]);
            if (kt + 5 <= 24) {
                const int kg = (kt + 5) * 32 + l4 * 8;
                const bool ok = kg + 8 <= 784;
                xa[cur] = ld4g(xrow + kg, ok);
                xb[cur] = ld4g(xrow + kg + 4, ok);
            }
            #pragma unroll
            for (int nf = 0; nf < 8; ++nf)
                acc1[nf] = __builtin_amdgcn_mfma_f32_16x16x32_bf16(a, bB[nf], acc1[nf], 0, 0, 0);
            if (kt + 3 <= 24) {
                #pragma unroll
                for (int nf = 0; nf < 8; ++nf)
                    bB[nf] = *(const bf16x8*)&wb[(size_t)((kt + 3) * 8 + nf) * 512 + lane * 8];
            }
        }
    }
    {   // tail kt=24 (even -> bA, slot 0)
        const bf16x8 a = cvt8(xa[0], xb[0]);
        #pragma unroll
        for (int nf = 0; nf < 8; ++nf)
            acc1[nf] = __builtin_amdgcn_mfma_f32_16x16x32_bf16(a, bA[nf], acc1[nf], 0, 0, 0);
    }

    // preload L2 fragment groups (kt=0) so latency hides under h1 epilogue
    const short* w2p = wb + W2P;
    bf16x8 g0[8], g1[8];
    #pragma unroll
    for (int nf = 0; nf < 8; ++nf) g0[nf] = *(const bf16x8*)&w2p[(size_t)(0 * 16 + nf) * 512 + lane * 8];
    #pragma unroll
    for (int nf = 0; nf < 8; ++nf) g1[nf] = *(const bf16x8*)&w2p[(size_t)(0 * 16 + 8 + nf) * 512 + lane * 8];

    // L1 epilogue: bias+relu -> h1 [16][128] (XOR-swizzled), wave-private
    #pragma unroll
    for (int nf = 0; nf < 8; ++nf) {
        const int c = nf * 16 + l15;
        const float bc = b1v[c];
        #pragma unroll
        for (int i = 0; i < 4; ++i) {
            const int r = l4 * 4 + i;
            const float h = fmaxf(acc1[nf][i] + bc, 0.f);
            hb[r * 128 + (((c >> 3) ^ (r & 7)) << 3) + (c & 7)] = f2bf(h);
        }
    }
    bf16x8 a2[4];
    #pragma unroll
    for (int kk = 0; kk < 4; ++kk)
        a2[kk] = *(const bf16x8*)&hb[l15 * 128 + (((kk * 4 + l4) ^ (l15 & 7)) << 3)];

    // ================= Layer 2: 4 K-tiles, ping-pong fragment halves ==========
    f32x4 acc2[16];
    #pragma unroll
    for (int nf = 0; nf < 16; ++nf) acc2[nf] = (f32x4){0.f,0.f,0.f,0.f};

    #pragma unroll
    for (int kt = 0; kt < 4; ++kt) {
        #pragma unroll
        for (int nf = 0; nf < 8; ++nf)
            acc2[nf] = __builtin_amdgcn_mfma_f32_16x16x32_bf16(a2[kt], g0[nf], acc2[nf], 0, 0, 0);
        if (kt < 3) {
            #pragma unroll
            for (int nf = 0; nf < 8; ++nf)
                g0[nf] = *(const bf16x8*)&w2p[(size_t)((kt + 1) * 16 + nf) * 512 + lane * 8];
        }
        #pragma unroll
        for (int nf = 0; nf < 8; ++nf)
            acc2[8 + nf] = __builtin_amdgcn_mfma_f32_16x16x32_bf16(a2[kt], g1[nf], acc2[8 + nf], 0, 0, 0);
        if (kt < 3) {
            #pragma unroll
            for (int nf = 0; nf < 8; ++nf)
                g1[nf] = *(const bf16x8*)&w2p[(size_t)((kt + 1) * 16 + 8 + nf) * 512 + lane * 8];
        }
    }

    // preload w3 fragments (8KB, L2-hot) so latency hides under h2 epilogue
    const short* w3p = wb + W3P;
    bf16x8 w3r[8];
    #pragma unroll
    for (int kt = 0; kt < 8; ++kt)
        w3r[kt] = *(const bf16x8*)&w3p[(size_t)kt * 512 + lane * 8];

    // L2 epilogue: bias+relu -> h2 [16][256] (overlays h1; a2 consumed)
    #pragma unroll
    for (int nf = 0; nf < 16; ++nf) {
        const int c = nf * 16 + l15;
        const float bc = b2v[c];
        #pragma unroll
        for (int i = 0; i < 4; ++i) {
            const int r = l4 * 4 + i;
            const float h = fmaxf(acc2[nf][i] + bc, 0.f);
            hb[r * 256 + (((c >> 3) ^ (r & 7)) << 3) + (c & 7)] = f2bf(h);
        }
    }

    // ================= Layer 3 + log_softmax ==================================
    f32x4 acc3 = (f32x4){0.f,0.f,0.f,0.f};
    #pragma unroll
    for (int kt = 0; kt < 8; ++kt) {
        const bf16x8 a3 = *(const bf16x8*)&hb[l15 * 256 + (((kt * 4 + l4) ^ (l15 & 7)) << 3)];
        acc3 = __builtin_amdgcn_mfma_f32_16x16x32_bf16(a3, w3r[kt], acc3, 0, 0, 0);
    }

    const float b3c = (l15 < 10) ? b3v[l15] : 0.f;
    #pragma unroll
    for (int i = 0; i < 4; ++i) {
        const float v = acc3[i] + b3c;
        float m = (l15 < 10) ? v : -1e30f;
        #pragma unroll
        for (int off = 8; off; off >>= 1) m = fmaxf(m, __shfl_xor(m, off, 16));
        const float e = (l15 < 10) ? expf(v - m) : 0.f;
        float sum = e;
        #pragma unroll
        for (int off = 8; off; off >>= 1) sum += __shfl_xor(sum, off, 16);
        const float ls = m + logf(sum);
        if (l15 < 10) {
            const int r = r0 + l4 * 4 + i;
            out[(size_t)r * 10 + l15] = v - ls;
        }
    }
}

extern "C" void kernel_launch(void* const* d_in, const int* in_sizes, int n_in,
                              void* d_out, int out_size, void* d_ws, size_t ws_size,
                              hipStream_t stream) {
    const float* x  = (const float*)d_in[0];
    const float* w1 = (const float*)d_in[1];
    const float* b1 = (const float*)d_in[2];
    const float* w2 = (const float*)d_in[3];
    const float* b2 = (const float*)d_in[4];
    const float* w3 = (const float*)d_in[5];
    const float* b3 = (const float*)d_in[6];
    float* out = (float*)d_out;
    short* wb  = (short*)d_ws;   // needs WTOT*2 = 272KB scratch

    prep_pack<<<(NFRAG_TOT * 64 + TPB - 1) / TPB, TPB, 0, stream>>>(w1, w2, w3, wb);

    dim3 grid(32768 / 64), block(TPB);
    mnist_v7<<<grid, block, 0, stream>>>(x, b1, b2, b3, wb, out);
}